// Round 27
// baseline (1129.044 us; speedup 1.0000x reference)
//
#include <hip/hip_runtime.h>
#include <hip/hip_bf16.h>

#define D_DIM 3072
#define NTRAIN 16384
#define NTEST 8192

typedef __attribute__((ext_vector_type(4))) float f32x4;
typedef __attribute__((ext_vector_type(4))) int i32x4;
typedef __attribute__((ext_vector_type(8))) int i32x8;

__device__ __forceinline__ unsigned short f2bf(float f) {
  union { float f; unsigned u; } x; x.f = f;
  unsigned r = x.u + 0x7FFFu + ((x.u >> 16) & 1u);
  return (unsigned short)(r >> 16);
}

__device__ __forceinline__ float bf2f(unsigned short b) {
  union { unsigned u; float f; } x; x.u = ((unsigned)b) << 16;
  return x.f;
}

__device__ __forceinline__ i32x8 cmb(i32x4 lo, i32x4 hi) {
  i32x8 r;
  r[0] = lo[0]; r[1] = lo[1]; r[2] = lo[2]; r[3] = lo[3];
  r[4] = hi[0]; r[5] = hi[1]; r[6] = hi[2]; r[7] = hi[3];
  return r;
}

__device__ __forceinline__ void gload16(const void* g, void* l) {
  __builtin_amdgcn_global_load_lds(
      (const __attribute__((address_space(1))) void*)g,
      (__attribute__((address_space(3))) void*)l, 16, 0, 0);
}

// T1a: bijective chunked XCD swizzle + 8x8 supertile (needs gx%8==0, gy%8==0).
__device__ __forceinline__ void swz_tile(int& tileY, int& tileX) {
  const int gx = gridDim.x, gy = gridDim.y;
  const int L = blockIdx.y * gx + blockIdx.x;
  const int q = (gx * gy) >> 3;
  const int s = (L & 7) * q + (L >> 3);
  const int sid = s >> 6;
  const int t = s & 63;
  const int scols = gx >> 3;
  const int sy = sid / scols, sx = sid - sy * scols;
  tileY = sy * 8 + (t >> 3);
  tileX = sx * 8 + (t & 7);
}

// T1b: plain bijective chunked swizzle (needs nwg%8==0 only).
__device__ __forceinline__ void swz_lin(int& tileY, int& tileX) {
  const int gx = gridDim.x;
  const int nwg = gx * gridDim.y;
  const int L = blockIdx.y * gx + blockIdx.x;
  const int s = (L & 7) * (nwg >> 3) + (L >> 3);
  tileY = s / gx;
  tileX = s - tileY * gx;
}

// ---------------- pass 0 ----------------
__global__ void k_convert8(const float* __restrict__ in, unsigned char* __restrict__ out, long n8) {
  long i = (long)blockIdx.x * blockDim.x + threadIdx.x;
  long stride = (long)gridDim.x * blockDim.x;
  for (; i < n8; i += stride) {
    float4 a = reinterpret_cast<const float4*>(in)[i * 2];
    float4 b = reinterpret_cast<const float4*>(in)[i * 2 + 1];
    int w0 = __builtin_amdgcn_cvt_pk_fp8_f32(a.x, a.y, 0, false);
    w0 = __builtin_amdgcn_cvt_pk_fp8_f32(a.z, a.w, w0, true);
    int w1 = __builtin_amdgcn_cvt_pk_fp8_f32(b.x, b.y, 0, false);
    w1 = __builtin_amdgcn_cvt_pk_fp8_f32(b.z, b.w, w1, true);
    reinterpret_cast<int2*>(out)[i] = make_int2(w0, w1);
  }
}

// Mt8[n][k] = fp8(M[k][n]); ALSO copies M (f32) to Mout — fuses the old k_copy4
// (saves one full 75 MB read of M + a launch).
__global__ void k_transpose_fp8(const float* __restrict__ M, unsigned char* __restrict__ Mt,
                                float* __restrict__ Mout) {
  __shared__ float t[32][33];
  int bx = blockIdx.x * 32, by = blockIdx.y * 32;
  int tx = threadIdx.x, ty = threadIdx.y;
#pragma unroll
  for (int i = 0; i < 32; i += 8) {
    float v = M[(size_t)(by + ty + i) * D_DIM + bx + tx];
    t[ty + i][tx] = v;
    Mout[(size_t)(by + ty + i) * D_DIM + bx + tx] = v;
  }
  __syncthreads();
#pragma unroll
  for (int i = 0; i < 32; i += 8) {
    float v = t[tx][ty + i];
    int p = __builtin_amdgcn_cvt_pk_fp8_f32(v, v, 0, false);
    Mt[(size_t)(bx + ty + i) * D_DIM + by + tx] = (unsigned char)(p & 0xFF);
  }
}

// ======== shared MX-fp8 mainloop: 256x256 tile, BK=128 (R21-exact, best measured) ========
__device__ __forceinline__ void mainloop4ph(const unsigned char* __restrict__ ga,
                                            const unsigned char* __restrict__ gb,
                                            unsigned char* As, unsigned char* Bs,
                                            int aRow0, int bRow0, int lhi, int tid,
                                            f32x4 acc[8][4]) {
  const int nt = D_DIM / 128;                    // 24
#pragma unroll
  for (int j = 0; j < 4; ++j) {
    gload16(ga + (size_t)j * 64 * D_DIM, As + j * 8192 + tid * 16);
    gload16(gb + (size_t)j * 64 * D_DIM, Bs + j * 8192 + tid * 16);
  }
  const int g0 = lhi, g1 = lhi ^ 4;
  for (int t = 0; t < nt; ++t) {
    const int p = t & 1;
    const unsigned char* Ac = As + p * 32768;
    const unsigned char* Bc = Bs + p * 32768;
    unsigned char* An = As + (p ^ 1) * 32768;
    unsigned char* Bn = Bs + (p ^ 1) * 32768;
    const bool stage = (t + 1 < nt);
    const int k1 = (t + 1) * 128;
    asm volatile("s_waitcnt vmcnt(0)" ::: "memory");
    __builtin_amdgcn_s_barrier();
    __builtin_amdgcn_sched_barrier(0);
    if (stage) {
#pragma unroll
      for (int j = 0; j < 4; ++j) {
        gload16(ga + (size_t)j * 64 * D_DIM + k1, An + j * 8192 + tid * 16);
        gload16(gb + (size_t)j * 64 * D_DIM + k1, Bn + j * 8192 + tid * 16);
      }
    }

#define RDA(q, H)                                                                    \
  cmb(*reinterpret_cast<const i32x4*>(                                               \
          &Ac[(aRow0 + (q) * 32 + (H) * 16) * 128 +                                  \
              ((g0 ^ ((aRow0 + (q) * 32 + (H) * 16) & 7)) * 16)]),                   \
      *reinterpret_cast<const i32x4*>(                                               \
          &Ac[(aRow0 + (q) * 32 + (H) * 16) * 128 +                                  \
              ((g1 ^ ((aRow0 + (q) * 32 + (H) * 16) & 7)) * 16)]))

#define MFMA8(q, A0, A1)                                                             \
  __builtin_amdgcn_s_setprio(1);                                                     \
  _Pragma("unroll") for (int n = 0; n < 4; ++n) {                                    \
    acc[(q) * 2][n] = __builtin_amdgcn_mfma_scale_f32_16x16x128_f8f6f4(              \
        A0, b8[n], acc[(q) * 2][n], 0, 0, 0, 127, 0, 127);                           \
    acc[(q) * 2 + 1][n] = __builtin_amdgcn_mfma_scale_f32_16x16x128_f8f6f4(          \
        A1, b8[n], acc[(q) * 2 + 1][n], 0, 0, 0, 127, 0, 127);                       \
  }                                                                                  \
  __builtin_amdgcn_s_setprio(0);                                                     \
  __builtin_amdgcn_sched_barrier(0);

    i32x8 b8[4];
#pragma unroll
    for (int n = 0; n < 4; ++n) {
      const int row = bRow0 + n * 16;
      const int f = row & 7;
      b8[n] = cmb(*reinterpret_cast<const i32x4*>(&Bc[row * 128 + ((g0 ^ f) * 16)]),
                  *reinterpret_cast<const i32x4*>(&Bc[row * 128 + ((g1 ^ f) * 16)]));
    }
    i32x8 a0 = RDA(0, 0), a1 = RDA(0, 1);
    __builtin_amdgcn_sched_barrier(0);
    i32x8 p0 = RDA(1, 0), p1 = RDA(1, 1);
    MFMA8(0, a0, a1)
    a0 = RDA(2, 0); a1 = RDA(2, 1);
    MFMA8(1, p0, p1)
    p0 = RDA(3, 0); p1 = RDA(3, 1);
    MFMA8(2, a0, a1)
    MFMA8(3, p0, p1)
#undef RDA
#undef MFMA8
  }
}

// ---- GEMM1: [x_train; x_test] @ M in ONE dispatch (rows 0..24575; xtr8/xte8
// contiguous in ws). norm = [s_n2 | c_n2] contiguous. sM8 written only for
// train tiles (tileY<64 — block-uniform). Epilogue dots vs fp8 X (R26). ----
__global__ __launch_bounds__(512, 2) void k_gemm_xm8(const unsigned char* __restrict__ X8,
                                                     const unsigned char* __restrict__ Mt8,
                                                     unsigned char* __restrict__ smOut,
                                                     float* __restrict__ norm) {
  __shared__ unsigned char As[2 * 256 * 128], Bs[2 * 256 * 128];
  const int tid = threadIdx.x, lane = tid & 63, wave = tid >> 6;
  const int wm = wave >> 2, wn = wave & 3;       // 2M x 4N
  const int l15 = lane & 15, lhi = lane >> 4;
  int tileY, tileX;
  swz_lin(tileY, tileX);                          // grid (12,96): nwg=1152 %8==0
  const int rowBase = tileY * 256, colBase = tileX * 256;
  const bool writeSm = (tileY < NTRAIN / 256);    // block-uniform
  const int srow = tid >> 3, ssl = tid & 7;
  const unsigned char* ga = X8 + (size_t)(rowBase + srow) * D_DIM + ((ssl ^ (srow & 7)) * 16);
  const unsigned char* gb = Mt8 + (size_t)(colBase + srow) * D_DIM + ((ssl ^ (srow & 7)) * 16);
  f32x4 acc[8][4] = {};
  mainloop4ph(ga, gb, As, Bs, wm * 128 + l15, wn * 64 + l15, lhi, tid, acc);
  __syncthreads();

  const int c0 = colBase + wn * 64 + l15;
#pragma unroll
  for (int m = 0; m < 8; ++m) {
#pragma unroll
    for (int r = 0; r < 4; ++r) {
      const size_t grow = rowBase + wm * 128 + m * 16 + lhi * 4 + r;
      float v = 0.f;
#pragma unroll
      for (int n = 0; n < 4; ++n) {
        float a = acc[m][n][r];
        const int gcol = c0 + n * 16;
        float xv = __builtin_amdgcn_cvt_f32_fp8((int)X8[grow * D_DIM + gcol], 0);
        v += a * xv;
        if (writeSm) {
          int pk = __builtin_amdgcn_cvt_pk_fp8_f32(a, a, 0, false);
          smOut[grow * D_DIM + gcol] = (unsigned char)(pk & 0xFF);
        }
      }
      v += __shfl_xor(v, 1); v += __shfl_xor(v, 2);
      v += __shfl_xor(v, 4); v += __shfl_xor(v, 8);
      if ((lane & 15) == 0) atomicAdd(&norm[grow], v);
    }
  }
}

// ---- GEMM2: MX-fp8, STORE-ONLY epilogue -> bf16 S half (R21-exact) ----
__global__ __launch_bounds__(512, 2) void k_gemm_cross(const unsigned char* __restrict__ sM8,
                                                       const unsigned char* __restrict__ xte8h,
                                                       const float* __restrict__ sn2,
                                                       const float* __restrict__ cn2h,
                                                       unsigned short* __restrict__ S) {
  __shared__ unsigned char As[2 * 256 * 128], Bs[2 * 256 * 128];
  const int tid = threadIdx.x, lane = tid & 63, wave = tid >> 6;
  const int wm = wave >> 2, wn = wave & 3;
  const int l15 = lane & 15, lhi = lane >> 4;
  int tileY, tileX;
  swz_tile(tileY, tileX);
  const int rowBase = tileY * 256, colBase = tileX * 256;
  const int srow = tid >> 3, ssl = tid & 7;
  const unsigned char* ga = sM8 + (size_t)(rowBase + srow) * D_DIM + ((ssl ^ (srow & 7)) * 16);
  const unsigned char* gb = xte8h + (size_t)(colBase + srow) * D_DIM + ((ssl ^ (srow & 7)) * 16);
  const int bRow0 = wn * 64 + l15;
  f32x4 acc[8][4] = {};
  mainloop4ph(ga, gb, As, Bs, wm * 128 + l15, bRow0, lhi, tid, acc);
  __syncthreads();

  float* snlds = reinterpret_cast<float*>(As);     // [256]
  if (tid < 256) snlds[tid] = sn2[rowBase + tid];
  __syncthreads();
  float cn[4];
#pragma unroll
  for (int n = 0; n < 4; ++n) cn[n] = cn2h[colBase + bRow0 + n * 16];
#pragma unroll
  for (int m = 0; m < 8; ++m) {
#pragma unroll
    for (int r = 0; r < 4; ++r) {
      const int lrow = wm * 128 + m * 16 + lhi * 4 + r;
      const float sn = snlds[lrow];
      const size_t grow = rowBase + lrow;
#pragma unroll
      for (int n = 0; n < 4; ++n) {
        float d2 = sn + cn[n] - 2.f * acc[m][n][r];
        float kv = exp2f(-0.14426950408889634f * sqrtf(fmaxf(d2, 0.f)));
        S[grow * 4096 + colBase + bRow0 + n * 16] = f2bf(kv);
      }
    }
  }
}

// ---- k_out: weighted column reduction of one half of S -> part.
// R27: 4 columns/thread via ushort4 loads (8 B/lane coalescing sweet spot). ----
__global__ __launch_bounds__(256) void k_out(const unsigned short* __restrict__ S,
                                             const float* __restrict__ Y,
                                             float* __restrict__ part, int halfBase) {
  __shared__ float ylds[256 * 10];
  const int tid = threadIdx.x;
  const int sBase = blockIdx.y * 256;
  const int tloc0 = blockIdx.x * 1024 + tid * 4;   // 0..4095, 4 cols/thread
  for (int i = tid; i < 2560; i += 256) ylds[i] = Y[(size_t)sBase * 10 + i];
  __syncthreads();
  float num[4][10];
  float den[4] = {0.f, 0.f, 0.f, 0.f};
#pragma unroll
  for (int j = 0; j < 4; ++j)
#pragma unroll
    for (int c = 0; c < 10; ++c) num[j][c] = 0.f;
  for (int s = 0; s < 256; ++s) {
    ushort4 kv4 = *reinterpret_cast<const ushort4*>(&S[(size_t)(sBase + s) * 4096 + tloc0]);
    const float* yr = &ylds[s * 10];
    float kv[4] = {bf2f(kv4.x), bf2f(kv4.y), bf2f(kv4.z), bf2f(kv4.w)};
#pragma unroll
    for (int j = 0; j < 4; ++j) {
      den[j] += kv[j];
#pragma unroll
      for (int c = 0; c < 10; ++c) num[j][c] += kv[j] * yr[c];
    }
  }
#pragma unroll
  for (int j = 0; j < 4; ++j) {
    const int tglob = halfBase + tloc0 + j;
#pragma unroll
    for (int c = 0; c < 10; ++c)
      part[((size_t)blockIdx.y * 11 + c) * NTEST + tglob] = num[j][c];
    part[((size_t)blockIdx.y * 11 + 10) * NTEST + tglob] = den[j];
  }
}

// ---------------- final reduce ----------------
__global__ void k_reduce(const float* __restrict__ part, float* __restrict__ out) {
  int t = blockIdx.x * blockDim.x + threadIdx.x;
  float num[10] = {0, 0, 0, 0, 0, 0, 0, 0, 0, 0};
  float den = 0.f;
  for (int it = 0; it < NTRAIN / 256; ++it) {
    const float* p = part + (size_t)it * 11 * NTEST + t;
#pragma unroll
    for (int c = 0; c < 10; ++c) num[c] += p[(size_t)c * NTEST];
    den += p[(size_t)10 * NTEST];
  }
  float inv = 1.f / den;
#pragma unroll
  for (int c = 0; c < 10; ++c) out[(size_t)t * 10 + c] = num[c] * inv;
}

extern "C" void kernel_launch(void* const* d_in, const int* in_sizes, int n_in,
                              void* d_out, int out_size, void* d_ws, size_t ws_size,
                              hipStream_t stream) {
  const float* x_train = (const float*)d_in[0];
  const float* y_train = (const float*)d_in[1];
  const float* x_test  = (const float*)d_in[2];
  const float* M       = (const float*)d_in[3];
  float* out = (float*)d_out;

  char* ws = (char*)d_ws;
  unsigned char*  xtr8 = (unsigned char*)(ws + 0);            // 50331648 (rows 0..16383)
  unsigned char*  xte8 = (unsigned char*)(ws + 50331648);     // 25165824 (rows 16384..24575)
  unsigned char*  Mt8  = (unsigned char*)(ws + 75497472);     // 9437184
  unsigned char*  sM8  = (unsigned char*)(ws + 84934656);     // 50331648
  float* norm = (float*)(ws + 135266304);                     // 24576*4 = 98304 = [s_n2|c_n2]
  float* s_n2 = norm;
  float* c_n2 = norm + NTRAIN;
  float* part = (float*)(ws + 135364608);                     // 23068672
  unsigned short* S = (unsigned short*)(ws + 158433280);      // 134217728

  hipMemsetAsync(ws + 135266304, 0, 98304, stream);  // norm

  k_convert8<<<1024, 256, 0, stream>>>(x_train, xtr8, (long)NTRAIN * D_DIM / 8);
  k_convert8<<<1024, 256, 0, stream>>>(x_test, xte8, (long)NTEST * D_DIM / 8);
  k_transpose_fp8<<<dim3(96, 96), dim3(32, 8), 0, stream>>>(M, Mt8, out + 81920);

  // combined xm: rows 0..24575, grid (3072/256, 24576/256) = (12, 96)
  k_gemm_xm8<<<dim3(12, 96), 512, 0, stream>>>(xtr8, Mt8, sM8, norm);

  for (int h = 0; h < 2; ++h) {
    k_gemm_cross<<<dim3(16, 64), 512, 0, stream>>>(
        sM8, xte8 + (size_t)h * 4096 * D_DIM, s_n2, c_n2 + h * 4096, S);
    k_out<<<dim3(4, 64), 256, 0, stream>>>(S, y_train, part, h * 4096);
  }
  k_reduce<<<32, 256, 0, stream>>>(part, out);
}

// Round 28
// 1022.197 us; speedup vs baseline: 1.1045x; 1.1045x over previous
//
#include <hip/hip_runtime.h>
#include <hip/hip_bf16.h>

#define D_DIM 3072
#define NTRAIN 16384
#define NTEST 8192

typedef __attribute__((ext_vector_type(4))) float f32x4;
typedef __attribute__((ext_vector_type(4))) int i32x4;
typedef __attribute__((ext_vector_type(8))) int i32x8;

__device__ __forceinline__ unsigned short f2bf(float f) {
  union { float f; unsigned u; } x; x.f = f;
  unsigned r = x.u + 0x7FFFu + ((x.u >> 16) & 1u);
  return (unsigned short)(r >> 16);
}

__device__ __forceinline__ float bf2f(unsigned short b) {
  union { unsigned u; float f; } x; x.u = ((unsigned)b) << 16;
  return x.f;
}

__device__ __forceinline__ i32x8 cmb(i32x4 lo, i32x4 hi) {
  i32x8 r;
  r[0] = lo[0]; r[1] = lo[1]; r[2] = lo[2]; r[3] = lo[3];
  r[4] = hi[0]; r[5] = hi[1]; r[6] = hi[2]; r[7] = hi[3];
  return r;
}

__device__ __forceinline__ void gload16(const void* g, void* l) {
  __builtin_amdgcn_global_load_lds(
      (const __attribute__((address_space(1))) void*)g,
      (__attribute__((address_space(3))) void*)l, 16, 0, 0);
}

// T1a: bijective chunked XCD swizzle + 8x8 supertile (needs gx%8==0, gy%8==0).
__device__ __forceinline__ void swz_tile(int& tileY, int& tileX) {
  const int gx = gridDim.x, gy = gridDim.y;
  const int L = blockIdx.y * gx + blockIdx.x;
  const int q = (gx * gy) >> 3;
  const int s = (L & 7) * q + (L >> 3);
  const int sid = s >> 6;
  const int t = s & 63;
  const int scols = gx >> 3;
  const int sy = sid / scols, sx = sid - sy * scols;
  tileY = sy * 8 + (t >> 3);
  tileX = sx * 8 + (t & 7);
}

// T1b: plain bijective chunked swizzle (needs nwg%8==0 only).
__device__ __forceinline__ void swz_lin(int& tileY, int& tileX) {
  const int gx = gridDim.x;
  const int nwg = gx * gridDim.y;
  const int L = blockIdx.y * gx + blockIdx.x;
  const int s = (L & 7) * (nwg >> 3) + (L >> 3);
  tileY = s / gx;
  tileX = s - tileY * gx;
}

// ---------------- pass 0 ----------------
__global__ void k_convert8(const float* __restrict__ in, unsigned char* __restrict__ out, long n8) {
  long i = (long)blockIdx.x * blockDim.x + threadIdx.x;
  long stride = (long)gridDim.x * blockDim.x;
  for (; i < n8; i += stride) {
    float4 a = reinterpret_cast<const float4*>(in)[i * 2];
    float4 b = reinterpret_cast<const float4*>(in)[i * 2 + 1];
    int w0 = __builtin_amdgcn_cvt_pk_fp8_f32(a.x, a.y, 0, false);
    w0 = __builtin_amdgcn_cvt_pk_fp8_f32(a.z, a.w, w0, true);
    int w1 = __builtin_amdgcn_cvt_pk_fp8_f32(b.x, b.y, 0, false);
    w1 = __builtin_amdgcn_cvt_pk_fp8_f32(b.z, b.w, w1, true);
    reinterpret_cast<int2*>(out)[i] = make_int2(w0, w1);
  }
}

__global__ void k_copy4(const float4* __restrict__ in, float4* __restrict__ out, long n4) {
  long i = (long)blockIdx.x * blockDim.x + threadIdx.x;
  long stride = (long)gridDim.x * blockDim.x;
  for (; i < n4; i += stride) out[i] = in[i];
}

// Mt8[n][k] = fp8(M[k][n])
__global__ void k_transpose_fp8(const float* __restrict__ M, unsigned char* __restrict__ Mt) {
  __shared__ float t[32][33];
  int bx = blockIdx.x * 32, by = blockIdx.y * 32;
  int tx = threadIdx.x, ty = threadIdx.y;
#pragma unroll
  for (int i = 0; i < 32; i += 8)
    t[ty + i][tx] = M[(size_t)(by + ty + i) * D_DIM + bx + tx];
  __syncthreads();
#pragma unroll
  for (int i = 0; i < 32; i += 8) {
    float v = t[tx][ty + i];
    int p = __builtin_amdgcn_cvt_pk_fp8_f32(v, v, 0, false);
    Mt[(size_t)(bx + ty + i) * D_DIM + by + tx] = (unsigned char)(p & 0xFF);
  }
}

// ======== shared MX-fp8 mainloop: 256x256 tile, BK=128 (R21-exact, best measured) ========
// 8 waves (2M x 4N), wave tile 128x64, acc[8][4]=128 regs. LDS 128 KiB dbuf.
// mfma_scale_f32_16x16x128_f8f6f4, unit scales (E8M0=127) = exact fp8 math at 2x
// non-scaled rate. Granule pair (lhi, lhi^4), phys slot = g ^ (row&7) (0-conflict).
// One sync per tile (vmcnt(0)+s_barrier); depth-1 A-operand prefetch inside.
__device__ __forceinline__ void mainloop4ph(const unsigned char* __restrict__ ga,
                                            const unsigned char* __restrict__ gb,
                                            unsigned char* As, unsigned char* Bs,
                                            int aRow0, int bRow0, int lhi, int tid,
                                            f32x4 acc[8][4]) {
  const int nt = D_DIM / 128;                    // 24
#pragma unroll
  for (int j = 0; j < 4; ++j) {
    gload16(ga + (size_t)j * 64 * D_DIM, As + j * 8192 + tid * 16);
    gload16(gb + (size_t)j * 64 * D_DIM, Bs + j * 8192 + tid * 16);
  }
  const int g0 = lhi, g1 = lhi ^ 4;
  for (int t = 0; t < nt; ++t) {
    const int p = t & 1;
    const unsigned char* Ac = As + p * 32768;
    const unsigned char* Bc = Bs + p * 32768;
    unsigned char* An = As + (p ^ 1) * 32768;
    unsigned char* Bn = Bs + (p ^ 1) * 32768;
    const bool stage = (t + 1 < nt);
    const int k1 = (t + 1) * 128;
    asm volatile("s_waitcnt vmcnt(0)" ::: "memory");   // tile-t stage units landed
    __builtin_amdgcn_s_barrier();
    __builtin_amdgcn_sched_barrier(0);
    if (stage) {
#pragma unroll
      for (int j = 0; j < 4; ++j) {
        gload16(ga + (size_t)j * 64 * D_DIM + k1, An + j * 8192 + tid * 16);
        gload16(gb + (size_t)j * 64 * D_DIM + k1, Bn + j * 8192 + tid * 16);
      }
    }

#define RDA(q, H)                                                                    \
  cmb(*reinterpret_cast<const i32x4*>(                                               \
          &Ac[(aRow0 + (q) * 32 + (H) * 16) * 128 +                                  \
              ((g0 ^ ((aRow0 + (q) * 32 + (H) * 16) & 7)) * 16)]),                   \
      *reinterpret_cast<const i32x4*>(                                               \
          &Ac[(aRow0 + (q) * 32 + (H) * 16) * 128 +                                  \
              ((g1 ^ ((aRow0 + (q) * 32 + (H) * 16) & 7)) * 16)]))

#define MFMA8(q, A0, A1)                                                             \
  __builtin_amdgcn_s_setprio(1);                                                     \
  _Pragma("unroll") for (int n = 0; n < 4; ++n) {                                    \
    acc[(q) * 2][n] = __builtin_amdgcn_mfma_scale_f32_16x16x128_f8f6f4(              \
        A0, b8[n], acc[(q) * 2][n], 0, 0, 0, 127, 0, 127);                           \
    acc[(q) * 2 + 1][n] = __builtin_amdgcn_mfma_scale_f32_16x16x128_f8f6f4(          \
        A1, b8[n], acc[(q) * 2 + 1][n], 0, 0, 0, 127, 0, 127);                       \
  }                                                                                  \
  __builtin_amdgcn_s_setprio(0);                                                     \
  __builtin_amdgcn_sched_barrier(0);

    i32x8 b8[4];
#pragma unroll
    for (int n = 0; n < 4; ++n) {
      const int row = bRow0 + n * 16;
      const int f = row & 7;
      b8[n] = cmb(*reinterpret_cast<const i32x4*>(&Bc[row * 128 + ((g0 ^ f) * 16)]),
                  *reinterpret_cast<const i32x4*>(&Bc[row * 128 + ((g1 ^ f) * 16)]));
    }
    i32x8 a0 = RDA(0, 0), a1 = RDA(0, 1);
    __builtin_amdgcn_sched_barrier(0);
    i32x8 p0 = RDA(1, 0), p1 = RDA(1, 1);
    MFMA8(0, a0, a1)
    a0 = RDA(2, 0); a1 = RDA(2, 1);
    MFMA8(1, p0, p1)
    p0 = RDA(3, 0); p1 = RDA(3, 1);
    MFMA8(2, a0, a1)
    MFMA8(3, p0, p1)
#undef RDA
#undef MFMA8
  }
}

// ---- GEMM1: X @ M, MX-fp8. Epilogue: norm2 dot vs fp8 X (same data as A-operand,
// 4x fewer HBM bytes than f32). Optional sM8 write. ----
template <bool WRITE_SM>
__global__ __launch_bounds__(512, 2) void k_gemm_xm8(const unsigned char* __restrict__ X8,
                                                     const unsigned char* __restrict__ Mt8,
                                                     unsigned char* __restrict__ smOut,
                                                     float* __restrict__ norm) {
  __shared__ unsigned char As[2 * 256 * 128], Bs[2 * 256 * 128];
  const int tid = threadIdx.x, lane = tid & 63, wave = tid >> 6;
  const int wm = wave >> 2, wn = wave & 3;       // 2M x 4N
  const int l15 = lane & 15, lhi = lane >> 4;
  int tileY, tileX;
  swz_lin(tileY, tileX);
  const int rowBase = tileY * 256, colBase = tileX * 256;
  const int srow = tid >> 3, ssl = tid & 7;
  const unsigned char* ga = X8 + (size_t)(rowBase + srow) * D_DIM + ((ssl ^ (srow & 7)) * 16);
  const unsigned char* gb = Mt8 + (size_t)(colBase + srow) * D_DIM + ((ssl ^ (srow & 7)) * 16);
  f32x4 acc[8][4] = {};
  mainloop4ph(ga, gb, As, Bs, wm * 128 + l15, wn * 64 + l15, lhi, tid, acc);
  __syncthreads();

  const int c0 = colBase + wn * 64 + l15;
#pragma unroll
  for (int m = 0; m < 8; ++m) {
#pragma unroll
    for (int r = 0; r < 4; ++r) {
      const size_t grow = rowBase + wm * 128 + m * 16 + lhi * 4 + r;
      float v = 0.f;
#pragma unroll
      for (int n = 0; n < 4; ++n) {
        float a = acc[m][n][r];
        const int gcol = c0 + n * 16;
        float xv = __builtin_amdgcn_cvt_f32_fp8((int)X8[grow * D_DIM + gcol], 0);
        v += a * xv;
        if (WRITE_SM) {
          int pk = __builtin_amdgcn_cvt_pk_fp8_f32(a, a, 0, false);
          smOut[grow * D_DIM + gcol] = (unsigned char)(pk & 0xFF);
        }
      }
      v += __shfl_xor(v, 1); v += __shfl_xor(v, 2);
      v += __shfl_xor(v, 4); v += __shfl_xor(v, 8);
      if ((lane & 15) == 0) atomicAdd(&norm[grow], v);
    }
  }
}

// ---- GEMM2: MX-fp8, STORE-ONLY epilogue -> bf16 S half (R21-exact) ----
__global__ __launch_bounds__(512, 2) void k_gemm_cross(const unsigned char* __restrict__ sM8,
                                                       const unsigned char* __restrict__ xte8h,
                                                       const float* __restrict__ sn2,
                                                       const float* __restrict__ cn2h,
                                                       unsigned short* __restrict__ S) {
  __shared__ unsigned char As[2 * 256 * 128], Bs[2 * 256 * 128];
  const int tid = threadIdx.x, lane = tid & 63, wave = tid >> 6;
  const int wm = wave >> 2, wn = wave & 3;
  const int l15 = lane & 15, lhi = lane >> 4;
  int tileY, tileX;
  swz_tile(tileY, tileX);
  const int rowBase = tileY * 256, colBase = tileX * 256;
  const int srow = tid >> 3, ssl = tid & 7;
  const unsigned char* ga = sM8 + (size_t)(rowBase + srow) * D_DIM + ((ssl ^ (srow & 7)) * 16);
  const unsigned char* gb = xte8h + (size_t)(colBase + srow) * D_DIM + ((ssl ^ (srow & 7)) * 16);
  const int bRow0 = wn * 64 + l15;
  f32x4 acc[8][4] = {};
  mainloop4ph(ga, gb, As, Bs, wm * 128 + l15, bRow0, lhi, tid, acc);
  __syncthreads();

  float* snlds = reinterpret_cast<float*>(As);     // [256]
  if (tid < 256) snlds[tid] = sn2[rowBase + tid];
  __syncthreads();
  float cn[4];
#pragma unroll
  for (int n = 0; n < 4; ++n) cn[n] = cn2h[colBase + bRow0 + n * 16];
#pragma unroll
  for (int m = 0; m < 8; ++m) {
#pragma unroll
    for (int r = 0; r < 4; ++r) {
      const int lrow = wm * 128 + m * 16 + lhi * 4 + r;
      const float sn = snlds[lrow];
      const size_t grow = rowBase + lrow;
#pragma unroll
      for (int n = 0; n < 4; ++n) {
        float d2 = sn + cn[n] - 2.f * acc[m][n][r];
        float kv = exp2f(-0.14426950408889634f * sqrtf(fmaxf(d2, 0.f)));
        S[grow * 4096 + colBase + bRow0 + n * 16] = f2bf(kv);
      }
    }
  }
}

// ---- k_out: column-wise weighted reduction of one half of S -> part ----
__global__ __launch_bounds__(256) void k_out(const unsigned short* __restrict__ S,
                                             const float* __restrict__ Y,
                                             float* __restrict__ part, int halfBase) {
  __shared__ float ylds[256 * 10];
  const int tid = threadIdx.x;
  const int sBase = blockIdx.y * 256;
  const int tloc = blockIdx.x * 256 + tid;       // 0..4095
  const int tglob = halfBase + tloc;
  for (int i = tid; i < 2560; i += 256) ylds[i] = Y[(size_t)sBase * 10 + i];
  __syncthreads();
  float num[10] = {0, 0, 0, 0, 0, 0, 0, 0, 0, 0};
  float den = 0.f;
  for (int s = 0; s < 256; ++s) {
    float kv = bf2f(S[(size_t)(sBase + s) * 4096 + tloc]);
    const float* yr = &ylds[s * 10];
#pragma unroll
    for (int c = 0; c < 10; ++c) num[c] += kv * yr[c];
    den += kv;
  }
#pragma unroll
  for (int c = 0; c < 10; ++c)
    part[((size_t)blockIdx.y * 11 + c) * NTEST + tglob] = num[c];
  part[((size_t)blockIdx.y * 11 + 10) * NTEST + tglob] = den;
}

// ---------------- final reduce ----------------
__global__ void k_reduce(const float* __restrict__ part, float* __restrict__ out) {
  int t = blockIdx.x * blockDim.x + threadIdx.x;
  float num[10] = {0, 0, 0, 0, 0, 0, 0, 0, 0, 0};
  float den = 0.f;
  for (int it = 0; it < NTRAIN / 256; ++it) {
    const float* p = part + (size_t)it * 11 * NTEST + t;
#pragma unroll
    for (int c = 0; c < 10; ++c) num[c] += p[(size_t)c * NTEST];
    den += p[(size_t)10 * NTEST];
  }
  float inv = 1.f / den;
#pragma unroll
  for (int c = 0; c < 10; ++c) out[(size_t)t * 10 + c] = num[c] * inv;
}

extern "C" void kernel_launch(void* const* d_in, const int* in_sizes, int n_in,
                              void* d_out, int out_size, void* d_ws, size_t ws_size,
                              hipStream_t stream) {
  const float* x_train = (const float*)d_in[0];
  const float* y_train = (const float*)d_in[1];
  const float* x_test  = (const float*)d_in[2];
  const float* M       = (const float*)d_in[3];
  float* out = (float*)d_out;

  char* ws = (char*)d_ws;
  unsigned char*  xtr8 = (unsigned char*)(ws + 0);            // 50331648
  unsigned char*  xte8 = (unsigned char*)(ws + 50331648);     // 25165824
  unsigned char*  Mt8  = (unsigned char*)(ws + 75497472);     // 9437184
  unsigned char*  sM8  = (unsigned char*)(ws + 84934656);     // 50331648
  float* s_n2 = (float*)(ws + 135266304);                     // 65536
  float* c_n2 = (float*)(ws + 135331840);                     // 32768
  float* part = (float*)(ws + 135364608);                     // 23068672
  unsigned short* S = (unsigned short*)(ws + 158433280);      // 134217728

  hipMemsetAsync(ws + 135266304, 0, 98304, stream);  // s_n2 + c_n2

  k_convert8<<<1024, 256, 0, stream>>>(x_train, xtr8, (long)NTRAIN * D_DIM / 8);
  k_convert8<<<1024, 256, 0, stream>>>(x_test, xte8, (long)NTEST * D_DIM / 8);
  k_transpose_fp8<<<dim3(96, 96), dim3(32, 8), 0, stream>>>(M, Mt8);
  k_copy4<<<2048, 256, 0, stream>>>((const float4*)M, (float4*)(out + 81920),
                                    (long)D_DIM * D_DIM / 4);

  k_gemm_xm8<true><<<dim3(12, 64), 512, 0, stream>>>(xtr8, Mt8, sM8, s_n2);
  k_gemm_xm8<false><<<dim3(12, 32), 512, 0, stream>>>(xte8, Mt8, nullptr, c_n2);

  for (int h = 0; h < 2; ++h) {
    k_gemm_cross<<<dim3(16, 64), 512, 0, stream>>>(
        sM8, xte8 + (size_t)h * 4096 * D_DIM, s_n2, c_n2 + h * 4096, S);
    k_out<<<dim3(16, 64), 256, 0, stream>>>(S, y_train, part, h * 4096);
  }
  k_reduce<<<32, 256, 0, stream>>>(part, out);
}